// Round 1
// 1163.914 us; speedup vs baseline: 1.6289x; 1.6289x over previous
//
#include <hip/hip_runtime.h>

typedef unsigned short u16;
typedef unsigned int u32;
typedef __bf16 bf16x8 __attribute__((ext_vector_type(8)));
typedef float f32x4 __attribute__((ext_vector_type(4)));
typedef u16 u16x4 __attribute__((ext_vector_type(4)));

#define B_ 4
#define S_ 1024
#define D_ 4096
#define H_ 32
#define KVH_ 8
#define HD_ 128
#define NTOK (B_*S_)      // 4096 tokens
#define TTOT 2048
#define STARTP 1024

__device__ __forceinline__ float b2f(u16 x){ u32 u = ((u32)x) << 16; return __builtin_bit_cast(float, u); }
__device__ __forceinline__ u16 f2b(float f){
  u32 u = __builtin_bit_cast(u32, f);
  u32 r = (u + 0x7fffu + ((u >> 16) & 1u)) >> 16;
  return (u16)r;
}

__device__ __forceinline__ void gl2lds16(const u16* g, u16* l){
  __builtin_amdgcn_global_load_lds(
      (const __attribute__((address_space(1))) u32*)g,
      (__attribute__((address_space(3))) u32*)l, 16, 0, 0);
}

// ---------------------------------------------------------------------------
// C[M][N] = A[M][K] * B[K][N], with B supplied transposed: BT[N][K].
// A, BT bf16; C is bf16 (u16) or fp32 per template. 128x128 tile, BK=32.
// ---------------------------------------------------------------------------
template <typename OT>
__global__ __launch_bounds__(256) void gemm_bt(const u16* __restrict__ A,
                                               const u16* __restrict__ BT,
                                               OT* __restrict__ C,
                                               int M, int N, int K)
{
  __shared__ __align__(16) u16 lA[128*32];
  __shared__ __align__(16) u16 lB[128*32];
  const int tid  = threadIdx.x;
  const int wave = tid >> 6, lane = tid & 63;
  const int q4 = lane >> 4, l15 = lane & 15;
  const int m0 = blockIdx.y * 128, n0 = blockIdx.x * 128;
  const int wm = (wave >> 1) * 64, wn = (wave & 1) * 64;
  const int srow = tid >> 2;        // 0..63
  const int scol = (tid & 3) * 8;   // 0,8,16,24

  const u16* ga = A  + (size_t)(m0 + srow) * K + scol;
  const u16* gb = BT + (size_t)(n0 + srow) * K + scol;

  f32x4 acc[4][4];
  #pragma unroll
  for (int i = 0; i < 4; i++)
    #pragma unroll
    for (int j = 0; j < 4; j++) acc[i][j] = (f32x4){0.f, 0.f, 0.f, 0.f};

  for (int k0 = 0; k0 < K; k0 += 32) {
    __builtin_amdgcn_s_waitcnt(0);
    __syncthreads();                      // previous iter's LDS reads done
    gl2lds16(ga + k0,                 &lA[tid * 8]);
    gl2lds16(ga + k0 + (size_t)64*K,  &lA[2048 + tid * 8]);
    gl2lds16(gb + k0,                 &lB[tid * 8]);
    gl2lds16(gb + k0 + (size_t)64*K,  &lB[2048 + tid * 8]);
    __builtin_amdgcn_s_waitcnt(0);        // drain global_load_lds
    __syncthreads();

    bf16x8 af[4], bb[4];
    #pragma unroll
    for (int mt = 0; mt < 4; mt++)
      af[mt] = *(const bf16x8*)&lA[(wm + mt*16 + l15) * 32 + q4 * 8];
    #pragma unroll
    for (int nt = 0; nt < 4; nt++)
      bb[nt] = *(const bf16x8*)&lB[(wn + nt*16 + l15) * 32 + q4 * 8];
    #pragma unroll
    for (int mt = 0; mt < 4; mt++)
      #pragma unroll
      for (int nt = 0; nt < 4; nt++)
        acc[mt][nt] = __builtin_amdgcn_mfma_f32_16x16x32_bf16(af[mt], bb[nt], acc[mt][nt], 0, 0, 0);
  }

  // C/D layout: row = q4*4+reg, col = l15
  #pragma unroll
  for (int mt = 0; mt < 4; mt++) {
    #pragma unroll
    for (int r = 0; r < 4; r++) {
      int row = m0 + wm + mt*16 + q4*4 + r;
      OT* crow = C + (size_t)row * N + n0 + wn + l15;
      #pragma unroll
      for (int nt = 0; nt < 4; nt++) {
        if constexpr (sizeof(OT) == 2) crow[nt * 16] = f2b(acc[mt][nt][r]);
        else                           crow[nt * 16] = acc[mt][nt][r];
      }
    }
  }
}

// ---------------------------------------------------------------------------
// fp32 -> bf16 elementwise convert, 4 elems/thread
// ---------------------------------------------------------------------------
__global__ __launch_bounds__(256) void cvt(const float* __restrict__ in,
                                           u16* __restrict__ out, int n)
{
  int i = (blockIdx.x * 256 + threadIdx.x) * 4;
  if (i >= n) return;
  float4 v = *(const float4*)(in + i);
  u16x4 o; o[0]=f2b(v.x); o[1]=f2b(v.y); o[2]=f2b(v.z); o[3]=f2b(v.w);
  *(u16x4*)(out + i) = o;
}

// ---------------------------------------------------------------------------
// fp32 [R][C] -> bf16 out[C][R] (convert + transpose); grid = (C/64, R/64)
// ---------------------------------------------------------------------------
__global__ __launch_bounds__(256) void cvt_transpose(const float* __restrict__ in,
                                                     u16* __restrict__ out,
                                                     int R, int C)
{
  __shared__ u16 t[64][65];
  const int c0 = blockIdx.x * 64, r0 = blockIdx.y * 64;
  const int tid = threadIdx.x;
  const int lr = tid >> 4;
  const int lc = (tid & 15) * 4;
  #pragma unroll
  for (int i = 0; i < 4; i++) {
    int r = lr + i * 16;
    float4 v = *(const float4*)&in[(size_t)(r0 + r) * C + c0 + lc];
    t[r][lc] = f2b(v.x); t[r][lc+1] = f2b(v.y); t[r][lc+2] = f2b(v.z); t[r][lc+3] = f2b(v.w);
  }
  __syncthreads();
  #pragma unroll
  for (int i = 0; i < 4; i++) {
    int r = lr + i * 16;             // output row = input col
    u16x4 v;
    v[0] = t[lc][r]; v[1] = t[lc+1][r]; v[2] = t[lc+2][r]; v[3] = t[lc+3][r];
    *(u16x4*)&out[(size_t)(c0 + r) * R + r0 + lc] = v;
  }
}

// ---------------------------------------------------------------------------
// kall[b][g][t][hd] bf16:  t<1024 from fp32 cache_k[b][t][g][hd];
//                          t>=1024 from bf16 xk[(b*1024+t-1024)][g*128+hd]
// ---------------------------------------------------------------------------
__global__ __launch_bounds__(256) void build_k(const float* __restrict__ ck,
                                               const u16* __restrict__ xk,
                                               u16* __restrict__ kall)
{
  int i = (blockIdx.x * 256 + threadIdx.x) * 4;
  const int hd = i & 127;
  const int t  = (i >> 7) & 2047;
  const int g  = (i >> 18) & 7;
  const int b  = i >> 21;
  u16x4 o;
  if (t < 1024) {
    const float* src = ck + ((size_t)(b * 4096 + t) * 8 + g) * 128 + hd;
    float4 v = *(const float4*)src;
    o[0]=f2b(v.x); o[1]=f2b(v.y); o[2]=f2b(v.z); o[3]=f2b(v.w);
  } else {
    const u16* src = xk + (size_t)(b * 1024 + (t - 1024)) * 1024 + g * 128 + hd;
    o = *(const u16x4*)src;
  }
  *(u16x4*)(kall + i) = o;
}

// ---------------------------------------------------------------------------
// vT[b][g][hd][t] bf16 from fp32 cache_v (t<1024) / bf16 xv (t>=1024)
// grid.x = 2048 tiles of 64x64
// ---------------------------------------------------------------------------
__global__ __launch_bounds__(256) void build_vt(const float* __restrict__ cv,
                                                const u16* __restrict__ xv,
                                                u16* __restrict__ vT)
{
  __shared__ u16 t[64][65];
  const int id = blockIdx.x;
  const int ht = id & 1;
  const int tt = (id >> 1) & 31;
  const int g  = (id >> 6) & 7;
  const int b  = id >> 9;
  const int t0 = tt * 64, hd0 = ht * 64;
  const int tid = threadIdx.x;
  const int lr = tid >> 4, lc = (tid & 15) * 4;
  if (t0 < 1024) {
    const float* base = cv + ((size_t)(b * 4096 + t0) * 8 + g) * 128 + hd0;
    #pragma unroll
    for (int i = 0; i < 4; i++) {
      int r = lr + i * 16;             // local t
      float4 v = *(const float4*)&base[(size_t)r * 1024 + lc];
      t[r][lc] = f2b(v.x); t[r][lc+1] = f2b(v.y); t[r][lc+2] = f2b(v.z); t[r][lc+3] = f2b(v.w);
    }
  } else {
    const u16* base = xv + (size_t)(b * 1024 + (t0 - 1024)) * 1024 + g * 128 + hd0;
    #pragma unroll
    for (int i = 0; i < 4; i++) {
      int r = lr + i * 16;
      u16x4 v = *(const u16x4*)&base[(size_t)r * 1024 + lc];
      t[r][lc] = v[0]; t[r][lc+1] = v[1]; t[r][lc+2] = v[2]; t[r][lc+3] = v[3];
    }
  }
  __syncthreads();
  u16* obase = vT + ((size_t)((b * 8 + g) * 128 + hd0)) * 2048 + t0;
  #pragma unroll
  for (int i = 0; i < 4; i++) {
    int r = lr + i * 16;             // local hd
    u16x4 v;
    v[0] = t[lc][r]; v[1] = t[lc+1][r]; v[2] = t[lc+2][r]; v[3] = t[lc+3][r];
    *(u16x4*)&obase[(size_t)r * 2048 + lc] = v;
  }
}

// ---------------------------------------------------------------------------
// RoPE in place on bf16 x: [NTOK][nh*128]; pair (2i,2i+1), m = STARTP + tok%1024
// ---------------------------------------------------------------------------
__global__ __launch_bounds__(256) void rope(u16* __restrict__ x, int nh)
{
  const int idx = blockIdx.x * 256 + threadIdx.x;
  const int total = NTOK * nh * 64;
  if (idx >= total) return;
  const int i  = idx & 63;
  const int hh = (idx >> 6) % nh;
  const int tk = idx / (64 * nh);
  const int s  = tk & (S_ - 1);
  const float m = (float)(STARTP + s);
  const float freq = m * exp2f(-(float)(2 * i) * (13.287712379549449f / 128.0f));
  const float cs = cosf(freq), sn = sinf(freq);
  size_t off = (size_t)tk * (nh * 128) + hh * 128 + 2 * i;
  float a = b2f(x[off]), b = b2f(x[off + 1]);
  x[off]     = f2b(a * cs - b * sn);
  x[off + 1] = f2b(a * sn + b * cs);
}

// ---------------------------------------------------------------------------
// Attention v2: grid (16 s-tiles, 8 kv-groups, 4 batch), 1024 threads = 16
// waves = 4 heads x 4 row-chunks of 16 q-rows. K (64x128) and V^T (128x64)
// tiles staged in LDS via global_load_lds, double-buffered, shared by all 16
// waves (16x L2-traffic cut vs per-wave global streaming). Bank-conflict-free
// fragment reads via XOR swizzle (byte ^= (row&7)<<4), applied on the GLOBAL
// source address at staging time (global_load_lds dest must stay linear) and
// on the LDS read address (same involution both sides).
// LDS = 32K(K,dbuf) + 32K(V,dbuf) + 16K(P) = 80 KB -> 2 blocks/CU = 32 waves.
// ---------------------------------------------------------------------------
__global__ __launch_bounds__(1024) void attn(const u16* __restrict__ xq,
                                             const u16* __restrict__ kall,
                                             const u16* __restrict__ vT,
                                             u16* __restrict__ out)
{
  __shared__ __align__(16) u16 lK[2][64 * 128];   // [t][hd], swizzled
  __shared__ __align__(16) u16 lV[2][128 * 64];   // [hd][t], swizzled
  __shared__ __align__(16) u16 lP[16][16][32];    // per-wave P roundtrip

  const int tid = threadIdx.x;
  const int w = tid >> 6, lane = tid & 63;
  const int q4 = lane >> 4, l15 = lane & 15;
  const int st = blockIdx.x, g = blockIdx.y, b = blockIdx.z;
  const int h = g * 4 + (w & 3);
  const int srow = st * 64 + (w >> 2) * 16;

  // Q fragments (registers)
  const u16* qrow = xq + ((size_t)(b * S_ + srow + l15) * (H_ * HD_) + h * HD_) + q4 * 8;
  bf16x8 qf[4];
  #pragma unroll
  for (int kk = 0; kk < 4; kk++) qf[kk] = *(const bf16x8*)(qrow + kk * 32);

  f32x4 o[8];
  #pragma unroll
  for (int i = 0; i < 8; i++) o[i] = (f32x4){0.f, 0.f, 0.f, 0.f};
  float ls[4] = {0.f, 0.f, 0.f, 0.f};

  const u16* kb = kall + (size_t)(b * KVH_ + g) * TTOT * HD_;
  const u16* vb = vT   + (size_t)(b * KVH_ + g) * HD_ * TTOT;

  // staging: K tile 64 rows x 256B; thread stages 16B at dest = tid*16
  const int rk = tid >> 4;                    // K row 0..63
  const int ckb = (tid & 15) << 4;            // byte slot in row
  const u16* gK = kb + (size_t)rk * HD_ + ((ckb ^ ((rk & 7) << 4)) >> 1);
  // V tile 128 rows x 128B; thread stages 16B at dest = tid*16
  const int rv = tid >> 3;                    // V row (hd) 0..127
  const int cvb = (tid & 7) << 4;
  const u16* gV = vb + (size_t)rv * TTOT + ((cvb ^ ((rv & 7) << 4)) >> 1);

  u16* dK[2] = { &lK[0][0] + tid * 8, &lK[1][0] + tid * 8 };
  u16* dV[2] = { &lV[0][0] + tid * 8, &lV[1][0] + tid * 8 };

  u16 (*pw)[32] = lP[w];
  const float SC = 0.12751936438002815f;  // log2(e)/sqrt(128)
  const int xk0 = (l15 & 7) << 4;         // K-read row xor (rows l15, l15+16, +32, +48 share &7? no: per-c below)
  (void)xk0;

  // prologue: stage tile 0
  gl2lds16(gK, dK[0]);
  gl2lds16(gV, dV[0]);
  asm volatile("s_waitcnt vmcnt(0)" ::: "memory");
  __syncthreads();

  for (int t0 = 0; t0 < TTOT; t0 += 64) {
    const int cur = (t0 >> 6) & 1;
    if (t0 + 64 < TTOT) {                 // stage next tile into other buffer
      gl2lds16(gK + (size_t)(t0 + 64) * HD_, dK[cur ^ 1]);
      gl2lds16(gV + (t0 + 64),               dV[cur ^ 1]);
    }
    const u16* K0 = &lK[cur][0];
    const u16* V0 = &lV[cur][0];

    #pragma unroll
    for (int c = 0; c < 2; c++) {         // two 32-key chunks
      const int r0 = c * 32 + l15;        // K rows r0 and r0+16 (same &7)
      const int xr = (r0 & 7) << 4;
      f32x4 s0 = (f32x4){0.f,0.f,0.f,0.f}, s1 = (f32x4){0.f,0.f,0.f,0.f};
      #pragma unroll
      for (int kk = 0; kk < 4; kk++) {
        const int cb = ((kk << 6) + (q4 << 4)) ^ xr;   // swizzled byte off in row
        bf16x8 k0 = *(const bf16x8*)(K0 + r0 * 128 + (cb >> 1));
        bf16x8 k1 = *(const bf16x8*)(K0 + (r0 + 16) * 128 + (cb >> 1));
        s0 = __builtin_amdgcn_mfma_f32_16x16x32_bf16(qf[kk], k0, s0, 0, 0, 0);
        s1 = __builtin_amdgcn_mfma_f32_16x16x32_bf16(qf[kk], k1, s1, 0, 0, 0);
      }
      float p0[4], p1[4];
      #pragma unroll
      for (int r = 0; r < 4; r++) { p0[r] = exp2f(s0[r] * SC); p1[r] = exp2f(s1[r] * SC); }
      #pragma unroll
      for (int r = 0; r < 4; r++) {
        ls[r] += p0[r] + p1[r];
        pw[q4 * 4 + r][l15]      = f2b(p0[r]);   // P C-layout -> LDS
        pw[q4 * 4 + r][16 + l15] = f2b(p1[r]);
      }
      asm volatile("s_waitcnt lgkmcnt(0)" ::: "memory");  // wave-private region
      bf16x8 pf = *(const bf16x8*)&pw[l15][q4 * 8];       // P A-layout
      const int xv2 = (l15 & 7) << 4;                     // V row xor (rv&7 == l15&7)
      #pragma unroll
      for (int nt = 0; nt < 8; nt++) {
        const int rvv = nt * 16 + l15;
        const int cb = ((c << 6) + (q4 << 4)) ^ xv2;
        bf16x8 vf = *(const bf16x8*)(V0 + rvv * 64 + (cb >> 1));
        o[nt] = __builtin_amdgcn_mfma_f32_16x16x32_bf16(pf, vf, o[nt], 0, 0, 0);
      }
    }

    asm volatile("s_waitcnt vmcnt(0)" ::: "memory");  // staged loads landed
    __syncthreads();                                  // all waves done w/ cur
  }

  #pragma unroll
  for (int r = 0; r < 4; r++) {
    #pragma unroll
    for (int m = 1; m < 16; m <<= 1) ls[r] += __shfl_xor(ls[r], m, 64);
    ls[r] = 1.0f / ls[r];
  }
  #pragma unroll
  for (int r = 0; r < 4; r++) {
    u16* orow = out + (size_t)(b * S_ + srow + q4 * 4 + r) * (H_ * HD_) + h * HD_ + l15;
    #pragma unroll
    for (int nt = 0; nt < 8; nt++)
      orow[nt * 16] = f2b(o[nt][r] * ls[r]);
  }
}

// ---------------------------------------------------------------------------
extern "C" void kernel_launch(void* const* d_in, const int* in_sizes, int n_in,
                              void* d_out, int out_size, void* d_ws, size_t ws_size,
                              hipStream_t stream)
{
  (void)in_sizes; (void)n_in; (void)out_size; (void)ws_size;
  const float* x  = (const float*)d_in[0];
  const float* wq = (const float*)d_in[1];
  const float* wk = (const float*)d_in[2];
  const float* wv = (const float*)d_in[3];
  const float* wo = (const float*)d_in[4];
  const float* ck = (const float*)d_in[5];
  const float* cv = (const float*)d_in[6];

  u16* ws  = (u16*)d_ws;
  u16* wqT = ws;                   // 4096x4096
  u16* wkT = wqT + 16777216;       // 1024x4096
  u16* wvT = wkT + 4194304;        // 1024x4096
  u16* woT = wvT + 4194304;        // 4096x4096
  u16* xb  = woT + 16777216;       // 4096x4096 bf16 x  (reused later as ao)
  u16* xq  = xb  + 16777216;       // 4096x4096
  u16* xk  = xq  + 16777216;       // 4096x1024
  u16* xv  = xk  + 4194304;        // 4096x1024
  u16* kall= xv  + 4194304;        // 4 x 8 x 2048 x 128
  u16* vT  = kall+ 8388608;        // 4 x 8 x 128 x 2048
  // total 100,663,296 u16 = 192 MiB
  u16* ao  = xb;                   // alias: xb dead after QKV gemms

  cvt_transpose<<<dim3(64, 64), 256, 0, stream>>>(wq, wqT, 4096, 4096);
  cvt_transpose<<<dim3(16, 64), 256, 0, stream>>>(wk, wkT, 4096, 1024);
  cvt_transpose<<<dim3(16, 64), 256, 0, stream>>>(wv, wvT, 4096, 1024);
  cvt_transpose<<<dim3(64, 64), 256, 0, stream>>>(wo, woT, 4096, 4096);
  cvt<<<16384, 256, 0, stream>>>(x, xb, 16777216);

  gemm_bt<u16><<<dim3(32, 32), 256, 0, stream>>>(xb, wqT, xq, 4096, 4096, 4096);
  gemm_bt<u16><<<dim3(8, 32),  256, 0, stream>>>(xb, wkT, xk, 4096, 1024, 4096);
  gemm_bt<u16><<<dim3(8, 32),  256, 0, stream>>>(xb, wvT, xv, 4096, 1024, 4096);

  rope<<<32768, 256, 0, stream>>>(xq, 32);
  rope<<<8192, 256, 0, stream>>>(xk, 8);

  build_k<<<8192, 256, 0, stream>>>(ck, xk, kall);
  build_vt<<<2048, 256, 0, stream>>>(cv, xv, vT);

  attn<<<dim3(16, 8, 4), 1024, 0, stream>>>(xq, kall, vT, ao);

  gemm_bt<float><<<dim3(32, 32), 256, 0, stream>>>(ao, woT, (float*)d_out, 4096, 4096, 4096);
}

// Round 4
// 1005.715 us; speedup vs baseline: 1.8851x; 1.1573x over previous
//
#include <hip/hip_runtime.h>

typedef unsigned short u16;
typedef unsigned int u32;
typedef __bf16 bf16x8 __attribute__((ext_vector_type(8)));
typedef float f32x4 __attribute__((ext_vector_type(4)));
typedef u16 u16x4 __attribute__((ext_vector_type(4)));

#define B_ 4
#define S_ 1024
#define D_ 4096
#define H_ 32
#define KVH_ 8
#define HD_ 128
#define NTOK (B_*S_)      // 4096 tokens
#define TTOT 2048
#define STARTP 1024

__device__ __forceinline__ float b2f(u16 x){ u32 u = ((u32)x) << 16; return __builtin_bit_cast(float, u); }
__device__ __forceinline__ u16 f2b(float f){
  u32 u = __builtin_bit_cast(u32, f);
  u32 r = (u + 0x7fffu + ((u >> 16) & 1u)) >> 16;
  return (u16)r;
}

__device__ __forceinline__ void gl2lds16(const u16* g, u16* l){
  __builtin_amdgcn_global_load_lds(
      (const __attribute__((address_space(1))) u32*)g,
      (__attribute__((address_space(3))) u32*)l, 16, 0, 0);
}

__device__ __forceinline__ void pbar(){
  __builtin_amdgcn_sched_barrier(0);
  __builtin_amdgcn_s_barrier();
  __builtin_amdgcn_sched_barrier(0);
}

// ---------------------------------------------------------------------------
// 256x256-tile 8-phase GEMM (HK-schedule port, per m201 template).
// C[M][N] = A[M][K] * BT[N][K]^T. 512 threads = 8 waves (2M x 4N), BK=64.
// LDS 128 KiB: [dbuf][slot][128x64 bf16], slots: 0=A-half0,1=A-half1,2=B-half0,
// 3=B-half1.
//
// Read schedule per tile (buf D): ph0: A-frags 0-3 + B-frags 0-1;
// ph1: B-frags 2-3; ph2: A-frags 4-7; ph3: none.
// Stage schedule per tile:        ph0: T+1.A1 -> buf D^1;
// ph1: none; ph2: T+2.B0 -> buf D; ph3: T+2.B1 + T+2.A0 -> buf D.
// RACE-FIX: A slots are read in BOTH ph0 and ph2 (lda_half slot depends on
// wm, not phase), so the A0 overwrite (T+2.A0) issues in ph3 only. Every
// staged slot's last reader consumed the data (lgkmcnt before its MFMAs)
// one barrier before the overwriting stage issues -> race-free by ordering.
// vmcnt(6) at tile end retires everything through this tile's ph0 stage
// (= all of tile T+1's slots); the 6 left in flight are tile T+2's.
// ENDPGM-FIX: drain vmcnt(0) after the loop — in-flight global_load_lds
// write LDS, which is reallocated to another workgroup at exit.
// XOR swizzle byte^=(row&7)<<4 via pre-swizzled GLOBAL source (linear LDS
// dest) + swizzled ds_read.
// ---------------------------------------------------------------------------
template<int J, int DB>
__device__ __forceinline__ void stage256(const u16* g, size_t rowK64, int kof,
                                         u16* lds, int tid)
{
  constexpr int slot = (J==0) ? 0 : (J==3) ? 1 : (J==1) ? 2 : 3;
  u16* d = lds + DB*32768 + slot*8192 + tid*8;
  gl2lds16(g + kof, d);
  gl2lds16(g + kof + rowK64, d + 4096);
}

template<int D, int MH>
__device__ __forceinline__ void lda_half(const u16* lds, int wm, int l15,
                                         int q4, int xr, bf16x8 (&a)[4][2])
{
  const u16* Ab = lds + D*32768 + wm*8192;
  #pragma unroll
  for (int fi = 0; fi < 4; fi++) {
    const int r = (MH*4 + fi)*16 + l15;
    #pragma unroll
    for (int ks = 0; ks < 2; ks++)
      a[fi][ks] = *(const bf16x8*)(Ab + r*64 + (((ks*64 + q4*16) ^ xr) >> 1));
  }
}

template<int D, int NH>
__device__ __forceinline__ void ldb_half(const u16* lds, int bhalf, int browbase,
                                         int l15, int q4, int xr, bf16x8 (&b)[4][2])
{
  const u16* Bb = lds + D*32768 + (2 + bhalf)*8192;
  #pragma unroll
  for (int ei = 0; ei < 2; ei++) {
    const int r = browbase + (NH*2 + ei)*16 + l15;
    #pragma unroll
    for (int ks = 0; ks < 2; ks++)
      b[NH*2+ei][ks] = *(const bf16x8*)(Bb + r*64 + (((ks*64 + q4*16) ^ xr) >> 1));
  }
}

template<int MH, int NH>
__device__ __forceinline__ void mfma_quad(const bf16x8 (&a)[4][2],
                                          const bf16x8 (&b)[4][2],
                                          f32x4 (&acc)[8][4])
{
  __builtin_amdgcn_s_setprio(1);
  #pragma unroll
  for (int ks = 0; ks < 2; ks++)
    #pragma unroll
    for (int fi = 0; fi < 4; fi++)
      #pragma unroll
      for (int ei = 0; ei < 2; ei++)
        acc[MH*4+fi][NH*2+ei] = __builtin_amdgcn_mfma_f32_16x16x32_bf16(
            a[fi][ks], b[NH*2+ei][ks], acc[MH*4+fi][NH*2+ei], 0, 0, 0);
  __builtin_amdgcn_s_setprio(0);
}

template<int D>
__device__ __forceinline__ void tile4(u16* lds,
    const u16* gA0, const u16* gA1, const u16* gB0, const u16* gB1,
    size_t rowK64, int k1, int k2, int tid, int wm, int bhalf, int browbase,
    int l15, int q4, int xr,
    bf16x8 (&a)[4][2], bf16x8 (&b)[4][2], f32x4 (&acc)[8][4])
{
  // phase 0: reads A frags 0-3 + B frags 0-1; stages [t+1:A1] -> other buf
  lda_half<D,0>(lds, wm, l15, q4, xr, a);
  ldb_half<D,0>(lds, bhalf, browbase, l15, q4, xr, b);
  stage256<3, D^1>(gA1, rowK64, k1, lds, tid);
  pbar();
  mfma_quad<0,0>(a, b, acc);
  pbar();
  // phase 1: reads B frags 2-3; no stage
  ldb_half<D,1>(lds, bhalf, browbase, l15, q4, xr, b);
  pbar();
  mfma_quad<0,1>(a, b, acc);
  pbar();
  // phase 2: reads A frags 4-7; stages [t+2:B0] (B0 last read @ph1)
  lda_half<D,1>(lds, wm, l15, q4, xr, a);
  stage256<1, D>(gB0, rowK64, k2, lds, tid);
  pbar();
  mfma_quad<1,0>(a, b, acc);
  pbar();
  // phase 3: stages [t+2:B1] (last read @ph1) + [t+2:A0] (last read @ph2)
  stage256<2, D>(gB1, rowK64, k2, lds, tid);
  stage256<0, D>(gA0, rowK64, k2, lds, tid);
  pbar();
  mfma_quad<1,1>(a, b, acc);
  __builtin_amdgcn_sched_barrier(0);
  asm volatile("s_waitcnt vmcnt(6)" ::: "memory");
  __builtin_amdgcn_sched_barrier(0);
  __builtin_amdgcn_s_barrier();
  __builtin_amdgcn_sched_barrier(0);
}

template <typename OT>
__global__ __launch_bounds__(512, 2) void gemm256(const u16* __restrict__ A,
                                                  const u16* __restrict__ BT,
                                                  OT* __restrict__ C,
                                                  int M, int N, int K)
{
  __shared__ __align__(16) u16 lds[65536];   // 128 KiB
  const int tid = threadIdx.x;
  const int wave = tid >> 6, lane = tid & 63;
  const int q4 = lane >> 4, l15 = lane & 15;
  const int wm = wave >> 2, wn = wave & 3;
  const int bhalf = wn >> 1;
  const int browbase = (wn & 1) * 64;
  const int xr = (l15 & 7) << 4;

  // bijective XCD swizzle (nwg = 256, divisible by 8)
  const int nbx = N >> 8;
  const int nwg = (M >> 8) * nbx;
  const int cpx = nwg >> 3;
  const int bid = (int)blockIdx.x;
  const int swz = (bid & 7) * cpx + (bid >> 3);
  const int bm0 = (swz / nbx) << 8;
  const int bn0 = (swz % nbx) << 8;

  const int nt = K >> 6;
  const int ntm1 = nt - 1;

  // staging source addresses (pre-swizzled: col ^= (row&7)<<4 bytes)
  const int rb = tid >> 3;
  const int c_off = ((((tid & 7) ^ (rb & 7)) << 4) >> 1);
  const size_t rowK64 = (size_t)64 * K;
  const u16* gA0 = A + (size_t)(bm0 + rb) * K + c_off;
  const u16* gA1 = gA0 + (size_t)128 * K;
  const u16* gB0 = BT + (size_t)(bn0 + rb) * K + c_off;
  const u16* gB1 = gB0 + (size_t)128 * K;

  bf16x8 a[4][2], b[4][2];
  f32x4 acc[8][4];
  #pragma unroll
  for (int i = 0; i < 8; i++)
    #pragma unroll
    for (int j = 0; j < 4; j++) acc[i][j] = (f32x4){0.f, 0.f, 0.f, 0.f};

  // prologue: stream positions 0..6 = tile0{A0,B0,B1,A1} + tile1{A0,B0,B1}
  stage256<0,0>(gA0, rowK64, 0, lds, tid);
  stage256<1,0>(gB0, rowK64, 0, lds, tid);
  stage256<2,0>(gB1, rowK64, 0, lds, tid);
  stage256<3,0>(gA1, rowK64, 0, lds, tid);
  stage256<0,1>(gA0, rowK64, 64, lds, tid);
  stage256<1,1>(gB0, rowK64, 64, lds, tid);
  stage256<2,1>(gB1, rowK64, 64, lds, tid);
  asm volatile("s_waitcnt vmcnt(6)" ::: "memory");   // tile0 fully landed
  __builtin_amdgcn_sched_barrier(0);
  __builtin_amdgcn_s_barrier();
  __builtin_amdgcn_sched_barrier(0);

  for (int t = 0; t < nt; t += 2) {
    {
      const int k1 = (t+1 < ntm1 ? t+1 : ntm1) * 64;
      const int k2 = (t+2 < ntm1 ? t+2 : ntm1) * 64;
      tile4<0>(lds, gA0, gA1, gB0, gB1, rowK64, k1, k2, tid, wm, bhalf,
               browbase, l15, q4, xr, a, b, acc);
    }
    {
      const int k1 = (t+2 < ntm1 ? t+2 : ntm1) * 64;
      const int k2 = (t+3 < ntm1 ? t+3 : ntm1) * 64;
      tile4<1>(lds, gA0, gA1, gB0, gB1, rowK64, k1, k2, tid, wm, bhalf,
               browbase, l15, q4, xr, a, b, acc);
    }
  }

  // drain in-flight global_load_lds before workgroup exit (LDS is
  // deallocated at endpgm; a late-landing write would corrupt the next
  // workgroup's LDS).
  __builtin_amdgcn_sched_barrier(0);
  asm volatile("s_waitcnt vmcnt(0)" ::: "memory");
  __builtin_amdgcn_sched_barrier(0);

  // epilogue: C/D layout row = q4*4+reg, col = l15
  #pragma unroll
  for (int f = 0; f < 8; f++) {
    #pragma unroll
    for (int r = 0; r < 4; r++) {
      const int row = bm0 + wm*128 + f*16 + q4*4 + r;
      OT* crow = C + (size_t)row * N + bn0 + wn*64 + l15;
      #pragma unroll
      for (int e = 0; e < 4; e++) {
        if constexpr (sizeof(OT) == 2) crow[e*16] = f2b(acc[f][e][r]);
        else                           crow[e*16] = acc[f][e][r];
      }
    }
  }
}

// ---------------------------------------------------------------------------
// 128x128-tile GEMM (kept for the N=1024 K/V projections: 256 blocks -> full
// CU coverage, where 256^2 tiles would leave 3/4 of the chip idle).
// ---------------------------------------------------------------------------
template <typename OT>
__global__ __launch_bounds__(256) void gemm_bt(const u16* __restrict__ A,
                                               const u16* __restrict__ BT,
                                               OT* __restrict__ C,
                                               int M, int N, int K)
{
  __shared__ __align__(16) u16 lA[128*32];
  __shared__ __align__(16) u16 lB[128*32];
  const int tid  = threadIdx.x;
  const int wave = tid >> 6, lane = tid & 63;
  const int q4 = lane >> 4, l15 = lane & 15;
  const int m0 = blockIdx.y * 128, n0 = blockIdx.x * 128;
  const int wm = (wave >> 1) * 64, wn = (wave & 1) * 64;
  const int srow = tid >> 2;        // 0..63
  const int scol = (tid & 3) * 8;   // 0,8,16,24

  const u16* ga = A  + (size_t)(m0 + srow) * K + scol;
  const u16* gb = BT + (size_t)(n0 + srow) * K + scol;

  f32x4 acc[4][4];
  #pragma unroll
  for (int i = 0; i < 4; i++)
    #pragma unroll
    for (int j = 0; j < 4; j++) acc[i][j] = (f32x4){0.f, 0.f, 0.f, 0.f};

  for (int k0 = 0; k0 < K; k0 += 32) {
    __builtin_amdgcn_s_waitcnt(0);
    __syncthreads();                      // previous iter's LDS reads done
    gl2lds16(ga + k0,                 &lA[tid * 8]);
    gl2lds16(ga + k0 + (size_t)64*K,  &lA[2048 + tid * 8]);
    gl2lds16(gb + k0,                 &lB[tid * 8]);
    gl2lds16(gb + k0 + (size_t)64*K,  &lB[2048 + tid * 8]);
    __builtin_amdgcn_s_waitcnt(0);        // drain global_load_lds
    __syncthreads();

    bf16x8 af[4], bb[4];
    #pragma unroll
    for (int mt = 0; mt < 4; mt++)
      af[mt] = *(const bf16x8*)&lA[(wm + mt*16 + l15) * 32 + q4 * 8];
    #pragma unroll
    for (int nt = 0; nt < 4; nt++)
      bb[nt] = *(const bf16x8*)&lB[(wn + nt*16 + l15) * 32 + q4 * 8];
    #pragma unroll
    for (int mt = 0; mt < 4; mt++)
      #pragma unroll
      for (int nt = 0; nt < 4; nt++)
        acc[mt][nt] = __builtin_amdgcn_mfma_f32_16x16x32_bf16(af[mt], bb[nt], acc[mt][nt], 0, 0, 0);
  }

  // C/D layout: row = q4*4+reg, col = l15
  #pragma unroll
  for (int mt = 0; mt < 4; mt++) {
    #pragma unroll
    for (int r = 0; r < 4; r++) {
      int row = m0 + wm + mt*16 + q4*4 + r;
      OT* crow = C + (size_t)row * N + n0 + wn + l15;
      #pragma unroll
      for (int nt = 0; nt < 4; nt++) {
        if constexpr (sizeof(OT) == 2) crow[nt * 16] = f2b(acc[mt][nt][r]);
        else                           crow[nt * 16] = acc[mt][nt][r];
      }
    }
  }
}

// ---------------------------------------------------------------------------
// fp32 -> bf16 elementwise convert, 4 elems/thread
// ---------------------------------------------------------------------------
__global__ __launch_bounds__(256) void cvt(const float* __restrict__ in,
                                           u16* __restrict__ out, int n)
{
  int i = (blockIdx.x * 256 + threadIdx.x) * 4;
  if (i >= n) return;
  float4 v = *(const float4*)(in + i);
  u16x4 o; o[0]=f2b(v.x); o[1]=f2b(v.y); o[2]=f2b(v.z); o[3]=f2b(v.w);
  *(u16x4*)(out + i) = o;
}

// ---------------------------------------------------------------------------
// fp32 [R][C] -> bf16 out[C][R] (convert + transpose); grid = (C/64, R/64)
// ---------------------------------------------------------------------------
__global__ __launch_bounds__(256) void cvt_transpose(const float* __restrict__ in,
                                                     u16* __restrict__ out,
                                                     int R, int C)
{
  __shared__ u16 t[64][65];
  const int c0 = blockIdx.x * 64, r0 = blockIdx.y * 64;
  const int tid = threadIdx.x;
  const int lr = tid >> 4;
  const int lc = (tid & 15) * 4;
  #pragma unroll
  for (int i = 0; i < 4; i++) {
    int r = lr + i * 16;
    float4 v = *(const float4*)&in[(size_t)(r0 + r) * C + c0 + lc];
    t[r][lc] = f2b(v.x); t[r][lc+1] = f2b(v.y); t[r][lc+2] = f2b(v.z); t[r][lc+3] = f2b(v.w);
  }
  __syncthreads();
  #pragma unroll
  for (int i = 0; i < 4; i++) {
    int r = lr + i * 16;             // output row = input col
    u16x4 v;
    v[0] = t[lc][r]; v[1] = t[lc+1][r]; v[2] = t[lc+2][r]; v[3] = t[lc+3][r];
    *(u16x4*)&out[(size_t)(c0 + r) * R + r0 + lc] = v;
  }
}

// ---------------------------------------------------------------------------
// kall[b][g][t][hd] bf16:  t<1024 from fp32 cache_k[b][t][g][hd];
//                          t>=1024 from bf16 xk[(b*1024+t-1024)][g*128+hd]
// ---------------------------------------------------------------------------
__global__ __launch_bounds__(256) void build_k(const float* __restrict__ ck,
                                               const u16* __restrict__ xk,
                                               u16* __restrict__ kall)
{
  int i = (blockIdx.x * 256 + threadIdx.x) * 4;
  const int hd = i & 127;
  const int t  = (i >> 7) & 2047;
  const int g  = (i >> 18) & 7;
  const int b  = i >> 21;
  u16x4 o;
  if (t < 1024) {
    const float* src = ck + ((size_t)(b * 4096 + t) * 8 + g) * 128 + hd;
    float4 v = *(const float4*)src;
    o[0]=f2b(v.x); o[1]=f2b(v.y); o[2]=f2b(v.z); o[3]=f2b(v.w);
  } else {
    const u16* src = xk + (size_t)(b * 1024 + (t - 1024)) * 1024 + g * 128 + hd;
    o = *(const u16x4*)src;
  }
  *(u16x4*)(kall + i) = o;
}

// ---------------------------------------------------------------------------
// vT[b][g][hd][t] bf16 from fp32 cache_v (t<1024) / bf16 xv (t>=1024)
// grid.x = 2048 tiles of 64x64
// ---------------------------------------------------------------------------
__global__ __launch_bounds__(256) void build_vt(const float* __restrict__ cv,
                                                const u16* __restrict__ xv,
                                                u16* __restrict__ vT)
{
  __shared__ u16 t[64][65];
  const int id = blockIdx.x;
  const int ht = id & 1;
  const int tt = (id >> 1) & 31;
  const int g  = (id >> 6) & 7;
  const int b  = id >> 9;
  const int t0 = tt * 64, hd0 = ht * 64;
  const int tid = threadIdx.x;
  const int lr = tid >> 4, lc = (tid & 15) * 4;
  if (t0 < 1024) {
    const float* base = cv + ((size_t)(b * 4096 + t0) * 8 + g) * 128 + hd0;
    #pragma unroll
    for (int i = 0; i < 4; i++) {
      int r = lr + i * 16;             // local t
      float4 v = *(const float4*)&base[(size_t)r * 1024 + lc];
      t[r][lc] = f2b(v.x); t[r][lc+1] = f2b(v.y); t[r][lc+2] = f2b(v.z); t[r][lc+3] = f2b(v.w);
    }
  } else {
    const u16* base = xv + (size_t)(b * 1024 + (t0 - 1024)) * 1024 + g * 128 + hd0;
    #pragma unroll
    for (int i = 0; i < 4; i++) {
      int r = lr + i * 16;
      u16x4 v = *(const u16x4*)&base[(size_t)r * 1024 + lc];
      t[r][lc] = v[0]; t[r][lc+1] = v[1]; t[r][lc+2] = v[2]; t[r][lc+3] = v[3];
    }
  }
  __syncthreads();
  u16* obase = vT + ((size_t)((b * 8 + g) * 128 + hd0)) * 2048 + t0;
  #pragma unroll
  for (int i = 0; i < 4; i++) {
    int r = lr + i * 16;             // local hd
    u16x4 v;
    v[0] = t[lc][r]; v[1] = t[lc+1][r]; v[2] = t[lc+2][r]; v[3] = t[lc+3][r];
    *(u16x4*)&obase[(size_t)r * 2048 + lc] = v;
  }
}

// ---------------------------------------------------------------------------
// RoPE in place on bf16 x: [NTOK][nh*128]; pair (2i,2i+1), m = STARTP + tok%1024
// ---------------------------------------------------------------------------
__global__ __launch_bounds__(256) void rope(u16* __restrict__ x, int nh)
{
  const int idx = blockIdx.x * 256 + threadIdx.x;
  const int total = NTOK * nh * 64;
  if (idx >= total) return;
  const int i  = idx & 63;
  const int hh = (idx >> 6) % nh;
  const int tk = idx / (64 * nh);
  const int s  = tk & (S_ - 1);
  const float m = (float)(STARTP + s);
  const float freq = m * exp2f(-(float)(2 * i) * (13.287712379549449f / 128.0f));
  const float cs = cosf(freq), sn = sinf(freq);
  size_t off = (size_t)tk * (nh * 128) + hh * 128 + 2 * i;
  float a = b2f(x[off]), b = b2f(x[off + 1]);
  x[off]     = f2b(a * cs - b * sn);
  x[off + 1] = f2b(a * sn + b * cs);
}

// ---------------------------------------------------------------------------
// Attention v2: grid (16 s-tiles, 8 kv-groups, 4 batch), 1024 threads = 16
// waves = 4 heads x 4 row-chunks of 16 q-rows. K (64x128) and V^T (128x64)
// tiles staged in LDS via global_load_lds, double-buffered, shared by all 16
// waves. XOR swizzle byte^=(row&7)<<4 via pre-swizzled global source.
// LDS = 32K(K,dbuf) + 32K(V,dbuf) + 16K(P) = 80 KB -> 2 blocks/CU.
// ---------------------------------------------------------------------------
__global__ __launch_bounds__(1024) void attn(const u16* __restrict__ xq,
                                             const u16* __restrict__ kall,
                                             const u16* __restrict__ vT,
                                             u16* __restrict__ out)
{
  __shared__ __align__(16) u16 lK[2][64 * 128];   // [t][hd], swizzled
  __shared__ __align__(16) u16 lV[2][128 * 64];   // [hd][t], swizzled
  __shared__ __align__(16) u16 lP[16][16][32];    // per-wave P roundtrip

  const int tid = threadIdx.x;
  const int w = tid >> 6, lane = tid & 63;
  const int q4 = lane >> 4, l15 = lane & 15;
  const int st = blockIdx.x, g = blockIdx.y, b = blockIdx.z;
  const int h = g * 4 + (w & 3);
  const int srow = st * 64 + (w >> 2) * 16;

  // Q fragments (registers)
  const u16* qrow = xq + ((size_t)(b * S_ + srow + l15) * (H_ * HD_) + h * HD_) + q4 * 8;
  bf16x8 qf[4];
  #pragma unroll
  for (int kk = 0; kk < 4; kk++) qf[kk] = *(const bf16x8*)(qrow + kk * 32);

  f32x4 o[8];
  #pragma unroll
  for (int i = 0; i < 8; i++) o[i] = (f32x4){0.f, 0.f, 0.f, 0.f};
  float ls[4] = {0.f, 0.f, 0.f, 0.f};

  const u16* kb = kall + (size_t)(b * KVH_ + g) * TTOT * HD_;
  const u16* vb = vT   + (size_t)(b * KVH_ + g) * HD_ * TTOT;

  // staging: K tile 64 rows x 256B; thread stages 16B at dest = tid*16
  const int rk = tid >> 4;                    // K row 0..63
  const int ckb = (tid & 15) << 4;            // byte slot in row
  const u16* gK = kb + (size_t)rk * HD_ + ((ckb ^ ((rk & 7) << 4)) >> 1);
  // V tile 128 rows x 128B; thread stages 16B at dest = tid*16
  const int rv = tid >> 3;                    // V row (hd) 0..127
  const int cvb = (tid & 7) << 4;
  const u16* gV = vb + (size_t)rv * TTOT + ((cvb ^ ((rv & 7) << 4)) >> 1);

  u16* dK[2] = { &lK[0][0] + tid * 8, &lK[1][0] + tid * 8 };
  u16* dV[2] = { &lV[0][0] + tid * 8, &lV[1][0] + tid * 8 };

  u16 (*pw)[32] = lP[w];
  const float SC = 0.12751936438002815f;  // log2(e)/sqrt(128)

  // prologue: stage tile 0
  gl2lds16(gK, dK[0]);
  gl2lds16(gV, dV[0]);
  asm volatile("s_waitcnt vmcnt(0)" ::: "memory");
  __syncthreads();

  for (int t0 = 0; t0 < TTOT; t0 += 64) {
    const int cur = (t0 >> 6) & 1;
    if (t0 + 64 < TTOT) {                 // stage next tile into other buffer
      gl2lds16(gK + (size_t)(t0 + 64) * HD_, dK[cur ^ 1]);
      gl2lds16(gV + (t0 + 64),               dV[cur ^ 1]);
    }
    const u16* K0 = &lK[cur][0];
    const u16* V0 = &lV[cur][0];

    #pragma unroll
    for (int c = 0; c < 2; c++) {         // two 32-key chunks
      const int r0 = c * 32 + l15;        // K rows r0 and r0+16 (same &7)
      const int xr = (r0 & 7) << 4;
      f32x4 s0 = (f32x4){0.f,0.f,0.f,0.f}, s1 = (f32x4){0.f,0.f,0.f,0.f};
      #pragma unroll
      for (int kk = 0; kk < 4; kk++) {
        const int cb = ((kk << 6) + (q4 << 4)) ^ xr;   // swizzled byte off in row
        bf16x8 k0 = *(const bf16x8*)(K0 + r0 * 128 + (cb >> 1));
        bf16x8 k1 = *(const bf16x8*)(K0 + (r0 + 16) * 128 + (cb >> 1));
        s0 = __builtin_amdgcn_mfma_f32_16x16x32_bf16(qf[kk], k0, s0, 0, 0, 0);
        s1 = __builtin_amdgcn_mfma_f32_16x16x32_bf16(qf[kk], k1, s1, 0, 0, 0);
      }
      float p0[4], p1[4];
      #pragma unroll
      for (int r = 0; r < 4; r++) { p0[r] = exp2f(s0[r] * SC); p1[r] = exp2f(s1[r] * SC); }
      #pragma unroll
      for (int r = 0; r < 4; r++) {
        ls[r] += p0[r] + p1[r];
        pw[q4 * 4 + r][l15]      = f2b(p0[r]);   // P C-layout -> LDS
        pw[q4 * 4 + r][16 + l15] = f2b(p1[r]);
      }
      asm volatile("s_waitcnt lgkmcnt(0)" ::: "memory");  // wave-private region
      bf16x8 pf = *(const bf16x8*)&pw[l15][q4 * 8];       // P A-layout
      const int xv2 = (l15 & 7) << 4;                     // V row xor (rv&7 == l15&7)
      #pragma unroll
      for (int nt = 0; nt < 8; nt++) {
        const int rvv = nt * 16 + l15;
        const int cb = ((c << 6) + (q4 << 4)) ^ xv2;
        bf16x8 vf = *(const bf16x8*)(V0 + rvv * 64 + (cb >> 1));
        o[nt] = __builtin_amdgcn_mfma_f32_16x16x32_bf16(pf, vf, o[nt], 0, 0, 0);
      }
    }

    asm volatile("s_waitcnt vmcnt(0)" ::: "memory");  // staged loads landed
    __syncthreads();                                  // all waves done w/ cur
  }

  #pragma unroll
  for (int r = 0; r < 4; r++) {
    #pragma unroll
    for (int m = 1; m < 16; m <<= 1) ls[r] += __shfl_xor(ls[r], m, 64);
    ls[r] = 1.0f / ls[r];
  }
  #pragma unroll
  for (int r = 0; r < 4; r++) {
    u16* orow = out + (size_t)(b * S_ + srow + q4 * 4 + r) * (H_ * HD_) + h * HD_ + l15;
    #pragma unroll
    for (int nt = 0; nt < 8; nt++)
      orow[nt * 16] = f2b(o[nt][r] * ls[r]);
  }
}

// ---------------------------------------------------------------------------
extern "C" void kernel_launch(void* const* d_in, const int* in_sizes, int n_in,
                              void* d_out, int out_size, void* d_ws, size_t ws_size,
                              hipStream_t stream)
{
  (void)in_sizes; (void)n_in; (void)out_size; (void)ws_size;
  const float* x  = (const float*)d_in[0];
  const float* wq = (const float*)d_in[1];
  const float* wk = (const float*)d_in[2];
  const float* wv = (const float*)d_in[3];
  const float* wo = (const float*)d_in[4];
  const float* ck = (const float*)d_in[5];
  const float* cv = (const float*)d_in[6];

  u16* ws  = (u16*)d_ws;
  u16* wqT = ws;                   // 4096x4096
  u16* wkT = wqT + 16777216;       // 1024x4096
  u16* wvT = wkT + 4194304;        // 1024x4096
  u16* woT = wvT + 4194304;        // 4096x4096
  u16* xb  = woT + 16777216;       // 4096x4096 bf16 x  (reused later as ao)
  u16* xq  = xb  + 16777216;       // 4096x4096
  u16* xk  = xq  + 16777216;       // 4096x1024
  u16* xv  = xk  + 4194304;        // 4096x1024
  u16* kall= xv  + 4194304;        // 4 x 8 x 2048 x 128
  u16* vT  = kall+ 8388608;        // 4 x 8 x 128 x 2048
  // total 100,663,296 u16 = 192 MiB
  u16* ao  = xb;                   // alias: xb dead after QKV gemms

  cvt_transpose<<<dim3(64, 64), 256, 0, stream>>>(wq, wqT, 4096, 4096);
  cvt_transpose<<<dim3(16, 64), 256, 0, stream>>>(wk, wkT, 4096, 1024);
  cvt_transpose<<<dim3(16, 64), 256, 0, stream>>>(wv, wvT, 4096, 1024);
  cvt_transpose<<<dim3(64, 64), 256, 0, stream>>>(wo, woT, 4096, 4096);
  cvt<<<16384, 256, 0, stream>>>(x, xb, 16777216);

  gemm256<u16><<<dim3(256), 512, 0, stream>>>(xb, wqT, xq, 4096, 4096, 4096);
  gemm_bt<u16><<<dim3(8, 32),  256, 0, stream>>>(xb, wkT, xk, 4096, 1024, 4096);
  gemm_bt<u16><<<dim3(8, 32),  256, 0, stream>>>(xb, wvT, xv, 4096, 1024, 4096);

  rope<<<32768, 256, 0, stream>>>(xq, 32);
  rope<<<8192, 256, 0, stream>>>(xk, 8);

  build_k<<<8192, 256, 0, stream>>>(ck, xk, kall);
  build_vt<<<2048, 256, 0, stream>>>(cv, xv, vT);

  attn<<<dim3(16, 8, 4), 1024, 0, stream>>>(xq, kall, vT, ao);

  gemm256<float><<<dim3(256), 512, 0, stream>>>(ao, woT, (float*)d_out, 4096, 4096, 4096);
}